// Round 7
// baseline (1109.504 us; speedup 1.0000x reference)
//
#include <hip/hip_runtime.h>
#include <hip/hip_bf16.h>

typedef __bf16 bf16_t;
typedef bf16_t bf16x8 __attribute__((ext_vector_type(8)));
typedef float f32x4 __attribute__((ext_vector_type(4)));

#define N_ROWS 4096
#define DIM    2048
#define VOCAB  65536
#define IGN    (-100)

// ---------------- 256x256 4-phase/K-tile GEMM ------------------------------
#define BM 256
#define BN 256
#define BK 64
#define NT (DIM / BK)     // 32 K-tiles
#define NUNITS (4 * NT)   // 128 stage units (16KB each)

#define GLOAD_LDS16(gp, lp)                                                  \
  __builtin_amdgcn_global_load_lds(                                          \
      (const __attribute__((address_space(1))) void*)(gp),                   \
      (__attribute__((address_space(3))) void*)(lp), 16, 0, 0)

// fp32 -> bf16 pre-convert, 8 elems/thread/iter
__global__ __launch_bounds__(256)
void cvt_bf16(const float* __restrict__ src, bf16_t* __restrict__ dst, long n8) {
  long i = (long)blockIdx.x * 256 + threadIdx.x;
  long stride = (long)gridDim.x * 256;
  for (; i < n8; i += stride) {
    const float4* s = reinterpret_cast<const float4*>(src) + i * 2;
    float4 a = s[0], b = s[1];
    bf16x8 v = {(bf16_t)a.x, (bf16_t)a.y, (bf16_t)a.z, (bf16_t)a.w,
                (bf16_t)b.x, (bf16_t)b.y, (bf16_t)b.z, (bf16_t)b.w};
    *reinterpret_cast<bf16x8*>(dst + i * 8) = v;
  }
}

// 256x256 tile, BK=64, 8 waves (2M x 4N, each 128x64 out).
// Phase (kk, mq): MFMA acc[mq*4..mq*4+3][0..3] with af-half + bfr[kk].
// Per-phase ds_reads (8,4,8,4 per wave) keep the LDS pipe evenly loaded.
// Slot-lifetime-safe stage schedule: tile T stages units
// {ph0: 4T+6, ph1: 4T+9, ph2: 4T+8, ph3: 4T+11} -- each slot overwritten
// >=1 barrier after its last ds_read drained (lgkm(0) precedes MFMA which
// precedes the phase-end barrier). vmcnt(6) after ph3 MFMA completes
// everything through unit 4T+6 (FIFO) => all 4 units of tile T+1 present.
__global__ __launch_bounds__(512, 2)
void lce_gemm8(const bf16_t* __restrict__ Eb, const bf16_t* __restrict__ Cb,
               float* __restrict__ sumexp) {
  extern __shared__ unsigned char lds[];  // 131072
  const int tid = threadIdx.x;
  const int lane = tid & 63, wid = tid >> 6;
  const int wr = wid >> 2, wc = wid & 3;      // 2M x 4N waves
  const int l15 = lane & 15, lg = lane >> 4;

  // bijective XCD swizzle (nwg=4096, %8==0), row-tile fast for C reuse
  const int bid = blockIdx.x;
  const int wg = (bid & 7) * (((N_ROWS / BM) * (VOCAB / BN)) / 8) + (bid >> 3);
  const int brow = (wg & (N_ROWS / BM - 1)) * BM;
  const int bcol = (wg / (N_ROWS / BM)) * BN;

  // ---- staging precompute: per-thread 2 segments of 16B -------------------
  const int prel0 = (wid * 2) * 1024 + lane * 16;
  const int prel1 = (wid * 2 + 1) * 1024 + lane * 16;
  auto mkgoff = [&](int p) {
    int L = p >> 7, sub = p & 127;
    int sl = sub ^ ((L & 7) << 4);                  // inverse swizzle
    return (size_t)(L * 2 + (sl >> 6)) * DIM + (size_t)((sl & 63) >> 1);
  };
  const size_t goff0 = mkgoff(prel0), goff1 = mkgoff(prel1);

  const bf16_t* Ebase = Eb + (size_t)brow * DIM;
  const bf16_t* Cbase = Cb + (size_t)bcol * DIM;

  auto stage = [&](int ug) {   // ug = global unit index [0, NUNITS)
    const bf16_t* gb = ((ug & 1) ? Cbase : Ebase) +
                       (ug >> 2) * BK + ((ug >> 1) & 1) * 32;
    unsigned char* lb = lds + (ug & 7) * 16384;     // slot = ug mod 8
    GLOAD_LDS16(gb + goff0, lb + prel0);
    GLOAD_LDS16(gb + goff1, lb + prel1);
  };

  // ---- fragment ds_read addresses (swizzled) ------------------------------
  const int lane_off = (((l15 & 1) << 6) | (lg << 4)) ^ ((l15 >> 1) << 4);
  const int abase = wr * 8192 + (l15 >> 1) * 128 + lane_off;
  const int bbase = 16384 + wc * 4096 + (l15 >> 1) * 128 + lane_off;

  f32x4 acc[8][4];
#pragma unroll
  for (int mi = 0; mi < 8; ++mi)
#pragma unroll
    for (int ni = 0; ni < 4; ++ni) acc[mi][ni] = (f32x4){0.f, 0.f, 0.f, 0.f};

  // ---- prologue: stage units in steady-state FIFO order -------------------
  stage(1); stage(0); stage(3); stage(2); stage(5); stage(4); stage(7);
  asm volatile("s_waitcnt vmcnt(6)" ::: "memory");  // units 0..3 landed
  __builtin_amdgcn_s_barrier();

  bf16x8 af[4], bfr[2][4];

  for (int T = 0; T < NT; ++T) {
    const unsigned char* base = lds + (T & 1) * 65536;
#pragma unroll
    for (int ph = 0; ph < 4; ++ph) {
      const int kk = ph >> 1, mq = ph & 1;
      const unsigned char* ab = base + kk * 32768;
      // per-phase ds_reads (data present since tile-top barrier)
      if (mq == 0) {
#pragma unroll
        for (int mi = 0; mi < 4; ++mi)
          af[mi] = *reinterpret_cast<const bf16x8*>(ab + abase + mi * 1024);
#pragma unroll
        for (int t = 0; t < 4; ++t)
          bfr[kk][t] = *reinterpret_cast<const bf16x8*>(ab + bbase + t * 1024);
      } else {
#pragma unroll
        for (int mi = 0; mi < 4; ++mi)
          af[mi] = *reinterpret_cast<const bf16x8*>(ab + abase + (4 + mi) * 1024);
      }
      __builtin_amdgcn_sched_barrier(0);            // reads issue first
      const int sug = (ph == 0) ? 6 : (ph == 1) ? 9 : (ph == 2) ? 8 : 11;
      const int ug = 4 * T + sug;
      if (ug < NUNITS) stage(ug);
      asm volatile("s_waitcnt lgkmcnt(0)" ::: "memory");
      __builtin_amdgcn_sched_barrier(0);
      __builtin_amdgcn_s_setprio(1);
#pragma unroll
      for (int mi = 0; mi < 4; ++mi)
#pragma unroll
        for (int ni = 0; ni < 4; ++ni)
          acc[mq * 4 + mi][ni] = __builtin_amdgcn_mfma_f32_16x16x32_bf16(
              af[mi], bfr[kk][ni], acc[mq * 4 + mi][ni], 0, 0, 0);
      __builtin_amdgcn_s_setprio(0);
      if (ph == 3 && T < NT - 1) {
        if (T < NT - 2) asm volatile("s_waitcnt vmcnt(6)" ::: "memory");
        else            asm volatile("s_waitcnt vmcnt(0)" ::: "memory");
      }
      __builtin_amdgcn_s_barrier();
    }
  }

  // ---- epilogue: per-row sum of exp over this block's 256 vocab cols ------
  // C/D: col = l15 (vocab), row = brow + wr*128 + mi*16 + lg*4 + j.
#pragma unroll
  for (int mi = 0; mi < 8; ++mi) {
    float p[4];
#pragma unroll
    for (int j = 0; j < 4; ++j) {
      p[j] = 0.f;
#pragma unroll
      for (int ni = 0; ni < 4; ++ni) p[j] += __expf(acc[mi][ni][j]);
    }
#pragma unroll
    for (int m = 1; m < 16; m <<= 1)
#pragma unroll
      for (int j = 0; j < 4; ++j) p[j] += __shfl_xor(p[j], m, 64);
    if (l15 == 0) {
      const int row = brow + wr * 128 + mi * 16 + lg * 4;
#pragma unroll
      for (int j = 0; j < 4; ++j) atomicAdd(&sumexp[row + j], p[j]);
    }
  }
}

// ---------------- fallback path (fp32 reg-staged, 128^2 tile) --------------
#define FBM 128
#define FBN 128
#define FBK 64
#define FNK (DIM / FBK)
#define FTHREADS 512

__global__ __launch_bounds__(FTHREADS, 4)
void lce_gemm_f32(const float* __restrict__ E, const float* __restrict__ C,
                  float* __restrict__ sumexp) {
  extern __shared__ unsigned char lds[];
  const int tid  = threadIdx.x;
  const int brow = blockIdx.x * FBM;
  const int bcol = blockIdx.y * FBN;

  float4 ra[4], rb[4];
  auto ld = [&](int k0) {
#pragma unroll
    for (int i = 0; i < 4; ++i) {
      int f = tid + i * FTHREADS;
      int r = f >> 4;
      int c = (f & 15) << 2;
      ra[i] = *reinterpret_cast<const float4*>(&E[(size_t)(brow + r) * DIM + k0 + c]);
      rb[i] = *reinterpret_cast<const float4*>(&C[(size_t)(bcol + r) * DIM + k0 + c]);
    }
  };
  auto st = [&](int buf) {
    unsigned char* a = lds + buf * 32768;
    unsigned char* b = a + 16384;
#pragma unroll
    for (int i = 0; i < 4; ++i) {
      int f  = tid + i * FTHREADS;
      int r  = f >> 4;
      int cbb = (f & 15) << 3;
      int off = r * 128 + (cbb ^ ((r & 7) << 4));
      union { bf16_t h[4]; unsigned long long u; } pa, pb;
      pa.h[0] = (bf16_t)ra[i].x; pa.h[1] = (bf16_t)ra[i].y;
      pa.h[2] = (bf16_t)ra[i].z; pa.h[3] = (bf16_t)ra[i].w;
      pb.h[0] = (bf16_t)rb[i].x; pb.h[1] = (bf16_t)rb[i].y;
      pb.h[2] = (bf16_t)rb[i].z; pb.h[3] = (bf16_t)rb[i].w;
      *reinterpret_cast<unsigned long long*>(a + off) = pa.u;
      *reinterpret_cast<unsigned long long*>(b + off) = pb.u;
    }
  };

  f32x4 acc[4][2];
#pragma unroll
  for (int mi = 0; mi < 4; ++mi)
#pragma unroll
    for (int ni = 0; ni < 2; ++ni) acc[mi][ni] = (f32x4){0.f, 0.f, 0.f, 0.f};

  const int lane = tid & 63, wid = tid >> 6;
  const int wr = wid >> 2, wc = wid & 3;
  const int l15 = lane & 15, lg = lane >> 4;
  const int swz = (l15 & 7) << 4;

  auto comp = [&](int buf) {
    const unsigned char* a = lds + buf * 32768;
    const unsigned char* b = a + 16384;
#pragma unroll
    for (int kk = 0; kk < 2; ++kk) {
      const int cbase = (kk * 64 + lg * 16) ^ swz;
      bf16x8 af[4], bfr[2];
#pragma unroll
      for (int mi = 0; mi < 4; ++mi)
        af[mi] = *reinterpret_cast<const bf16x8*>(
            a + (wr * 64 + mi * 16 + l15) * 128 + cbase);
#pragma unroll
      for (int ni = 0; ni < 2; ++ni)
        bfr[ni] = *reinterpret_cast<const bf16x8*>(
            b + (wc * 32 + ni * 16 + l15) * 128 + cbase);
#pragma unroll
      for (int mi = 0; mi < 4; ++mi)
#pragma unroll
        for (int ni = 0; ni < 2; ++ni)
          acc[mi][ni] = __builtin_amdgcn_mfma_f32_16x16x32_bf16(
              af[mi], bfr[ni], acc[mi][ni], 0, 0, 0);
    }
  };

  ld(0);
  st(0);
  for (int kt = 0; kt < FNK; ++kt) {
    __syncthreads();
    if (kt + 1 < FNK) ld((kt + 1) * FBK);
    comp(kt & 1);
    if (kt + 1 < FNK) st((kt + 1) & 1);
  }

#pragma unroll
  for (int mi = 0; mi < 4; ++mi) {
    float p[4];
#pragma unroll
    for (int j = 0; j < 4; ++j)
      p[j] = __expf(acc[mi][0][j]) + __expf(acc[mi][1][j]);
#pragma unroll
    for (int m = 1; m < 16; m <<= 1)
#pragma unroll
      for (int j = 0; j < 4; ++j) p[j] += __shfl_xor(p[j], m, 64);
    if (l15 == 0) {
      int row = brow + wr * 64 + mi * 16 + lg * 4;
#pragma unroll
      for (int j = 0; j < 4; ++j) atomicAdd(&sumexp[row + j], p[j]);
    }
  }
}

// ---------------- exact fp32 target logit, one wave per row ----------------
__global__ __launch_bounds__(256)
void lce_tgt(const float* __restrict__ E, const float* __restrict__ C,
             const int* __restrict__ T, float* __restrict__ tgt) {
  int w = (int)((blockIdx.x * blockDim.x + threadIdx.x) >> 6);
  int lane = threadIdx.x & 63;
  if (w >= N_ROWS) return;
  int t = T[w];
  float s = 0.f;
  if (t != IGN) {
    const float4* er = reinterpret_cast<const float4*>(E + (size_t)w * DIM);
    const float4* cr = reinterpret_cast<const float4*>(C + (size_t)t * DIM);
#pragma unroll
    for (int i = 0; i < DIM / 4 / 64; ++i) {
      float4 a = er[lane + i * 64];
      float4 b = cr[lane + i * 64];
      s = fmaf(a.x, b.x, s); s = fmaf(a.y, b.y, s);
      s = fmaf(a.z, b.z, s); s = fmaf(a.w, b.w, s);
    }
#pragma unroll
    for (int m = 1; m < 64; m <<= 1) s += __shfl_xor(s, m, 64);
  }
  if (lane == 0) tgt[w] = s;
}

// ---------------- final scalar reduce --------------------------------------
__global__ __launch_bounds__(256)
void lce_finalize(const float* __restrict__ sumexp, const float* __restrict__ tgt,
                  const int* __restrict__ T, float* __restrict__ out) {
  int tid = threadIdx.x;
  float nll = 0.f, cnt = 0.f;
  for (int n = tid; n < N_ROWS; n += 256) {
    if (T[n] != IGN) {
      nll += logf(sumexp[n]) - tgt[n];
      cnt += 1.f;
    }
  }
#pragma unroll
  for (int m = 1; m < 64; m <<= 1) {
    nll += __shfl_xor(nll, m, 64);
    cnt += __shfl_xor(cnt, m, 64);
  }
  __shared__ float sn[4], sc[4];
  if ((tid & 63) == 0) { sn[tid >> 6] = nll; sc[tid >> 6] = cnt; }
  __syncthreads();
  if (tid == 0) {
    float a = 0.f, b = 0.f;
#pragma unroll
    for (int i = 0; i < 4; ++i) { a += sn[i]; b += sc[i]; }
    out[0] = a / fmaxf(b, 1.f);
  }
}

extern "C" void kernel_launch(void* const* d_in, const int* in_sizes, int n_in,
                              void* d_out, int out_size, void* d_ws, size_t ws_size,
                              hipStream_t stream) {
  const float* E = (const float*)d_in[0];
  const float* C = (const float*)d_in[1];
  const int*   T = (const int*)d_in[2];
  float* out = (float*)d_out;

  unsigned char* ws = (unsigned char*)d_ws;
  float* sumexp = (float*)ws;                        // 16 KB
  float* tgt    = (float*)(ws + 16384);              // 16 KB
  bf16_t* Ebf   = (bf16_t*)(ws + 32768);             // 16 MB
  bf16_t* Cbf   = (bf16_t*)(ws + 32768 + (size_t)N_ROWS * DIM * 2);

  const size_t need = 32768 + (size_t)N_ROWS * DIM * 2 + (size_t)VOCAB * DIM * 2;

  hipMemsetAsync(sumexp, 0, N_ROWS * sizeof(float), stream);

  if (ws_size >= need) {
    cvt_bf16<<<1024, 256, 0, stream>>>(E, Ebf, (long)N_ROWS * DIM / 8);
    cvt_bf16<<<4096, 256, 0, stream>>>(C, Cbf, (long)VOCAB * DIM / 8);
    lce_gemm8<<<dim3((N_ROWS / BM) * (VOCAB / BN)), 512, 131072, stream>>>(Ebf, Cbf, sumexp);
  } else {
    lce_gemm_f32<<<dim3(N_ROWS / FBM, VOCAB / FBN), FTHREADS, 65536, stream>>>(E, C, sumexp);
  }

  lce_tgt<<<dim3((N_ROWS * 64) / 256), 256, 0, stream>>>(E, C, T, tgt);
  lce_finalize<<<dim3(1), 256, 0, stream>>>(sumexp, tgt, T, out);
}

// Round 8
// 868.794 us; speedup vs baseline: 1.2771x; 1.2771x over previous
//
#include <hip/hip_runtime.h>
#include <hip/hip_bf16.h>
#include <hip/hip_fp8.h>

typedef __bf16 bf16_t;
typedef bf16_t bf16x8 __attribute__((ext_vector_type(8)));
typedef float f32x4 __attribute__((ext_vector_type(4)));
typedef float f32x16 __attribute__((ext_vector_type(16)));
typedef int   i32x4  __attribute__((ext_vector_type(4)));
typedef int   i32x8  __attribute__((ext_vector_type(8)));

#define N_ROWS 4096
#define DIM    2048
#define VOCAB  65536
#define IGN    (-100)

// ---------------- MX-fp8 256x256 GEMM, BK=128 ------------------------------
#define BM 256
#define BN 256
#define BK 128            // fp8 elems (=bytes) per K-tile
#define NT (DIM / BK)     // 16 K-tiles
#define NUNITS (4 * NT)   // 64 stage units (16KB each)
#define SCALE1 0x7F7F7F7F // e8m0 = 127 -> 1.0 in every byte

#define GLOAD_LDS16(gp, lp)                                                  \
  __builtin_amdgcn_global_load_lds(                                          \
      (const __attribute__((address_space(1))) void*)(gp),                   \
      (__attribute__((address_space(3))) void*)(lp), 16, 0, 0)

// fp32 -> fp8 e4m3 (OCP) with pre-scale; 16 elems/thread/iter
__global__ __launch_bounds__(256)
void cvt_fp8(const float* __restrict__ src, unsigned char* __restrict__ dst,
             long n16, float scale) {
  long i = (long)blockIdx.x * 256 + threadIdx.x;
  long stride = (long)gridDim.x * 256;
  for (; i < n16; i += stride) {
    const float4* s = reinterpret_cast<const float4*>(src) + i * 4;
    union { unsigned char b[16]; i32x4 v; } o;
#pragma unroll
    for (int q = 0; q < 4; ++q) {
      float4 a = s[q];
      o.b[q * 4 + 0] = __hip_fp8_e4m3(a.x * scale).__x;
      o.b[q * 4 + 1] = __hip_fp8_e4m3(a.y * scale).__x;
      o.b[q * 4 + 2] = __hip_fp8_e4m3(a.z * scale).__x;
      o.b[q * 4 + 3] = __hip_fp8_e4m3(a.w * scale).__x;
    }
    *reinterpret_cast<i32x4*>(dst + i * 16) = o.v;
  }
}

// 256x256 tile, BK=128, 8 waves (2M x 4N, each 128x64 out), MX-fp8 MFMA
// (32x32x64, unity scales; the x8 factor on C is undone via acc*0.125 in
// the epilogue). LDS 128KB = 8 slots x 16KB; unit u of tile T: 0=A[k0:64],
// 1=B[k0:64], 2=A[k64:128], 3=B[k64:128]; each [256r][64B] packed 2 rows
// per 128B line, swizzle phys_sub = sub ^ ((line&7)<<4) (inverse applied
// to the global source; LDS dest stays linear).
// Phase (ks,mq): 4 MFMA + {8,4,8,4} ds_reads. Stage schedule per tile:
// {ph0:4T+6, ph1:4T+9, ph2:4T+8, ph3:4T+11} -- every slot overwritten
// >=1 barrier after its reads drain. vmcnt(6) at ph3 guarantees tile T+1
// fully resident (FIFO). Prologue stages {0,1,2,3,4,5,7}.
__global__ __launch_bounds__(512, 2)
void lce_gemm_fp8(const unsigned char* __restrict__ E8,
                  const unsigned char* __restrict__ C8,
                  float* __restrict__ sumexp) {
  extern __shared__ unsigned char lds[];  // 131072
  const int tid = threadIdx.x;
  const int lane = tid & 63, wid = tid >> 6;
  const int wr = wid >> 2, wc = wid & 3;      // 2M x 4N waves
  const int l31 = lane & 31, lh = lane >> 5;

  // bijective XCD swizzle (nwg=4096, %8==0), row-tile fast for C reuse
  const int bid = blockIdx.x;
  const int wg = (bid & 7) * (((N_ROWS / BM) * (VOCAB / BN)) / 8) + (bid >> 3);
  const int brow = (wg & (N_ROWS / BM - 1)) * BM;
  const int bcol = (wg / (N_ROWS / BM)) * BN;

  // ---- staging: per-thread 2 segments of 16B ------------------------------
  const int prel0 = (wid * 2) * 1024 + lane * 16;
  const int prel1 = (wid * 2 + 1) * 1024 + lane * 16;
  auto mkgoff = [&](int p) {
    int L = p >> 7, sub = p & 127;
    int sl = sub ^ ((L & 7) << 4);                  // inverse swizzle
    return (size_t)(L * 2 + (sl >> 6)) * DIM + (size_t)(sl & 63);
  };
  const size_t goff0 = mkgoff(prel0), goff1 = mkgoff(prel1);

  const unsigned char* Ebase = E8 + (size_t)brow * DIM;
  const unsigned char* Cbase = C8 + (size_t)bcol * DIM;

  auto stage = [&](int ug) {   // ug = global unit index [0, NUNITS)
    const unsigned char* gb = ((ug & 1) ? Cbase : Ebase) +
                              (ug >> 2) * BK + ((ug >> 1) & 1) * 64;
    unsigned char* lb = lds + (ug & 7) * 16384;     // slot = ug mod 8
    GLOAD_LDS16(gb + goff0, lb + prel0);
    GLOAD_LDS16(gb + goff1, lb + prel1);
  };

  // ---- fragment read: row r, k-half lh from unit U ------------------------
  auto read_frag = [&](const unsigned char* U, int row) -> i32x8 {
    const int line = row >> 1;
    const int m = (line & 7) << 4;
    const int sub0 = ((row & 1) << 6) | (lh << 5);  // k0 byte = lh*32
    const unsigned char* p = U + line * 128;
    i32x4 lo = *reinterpret_cast<const i32x4*>(p + (sub0 ^ m));
    i32x4 hi = *reinterpret_cast<const i32x4*>(p + ((sub0 + 16) ^ m));
    return __builtin_shufflevector(lo, hi, 0, 1, 2, 3, 4, 5, 6, 7);
  };

  f32x16 acc[4][2];
#pragma unroll
  for (int mi = 0; mi < 4; ++mi)
#pragma unroll
    for (int ni = 0; ni < 2; ++ni)
#pragma unroll
      for (int r = 0; r < 16; ++r) acc[mi][ni][r] = 0.f;

  // ---- prologue -----------------------------------------------------------
  stage(0); stage(1); stage(2); stage(3); stage(4); stage(5); stage(7);
  asm volatile("s_waitcnt vmcnt(6)" ::: "memory");  // units 0..3 landed
  __builtin_amdgcn_s_barrier();

  i32x8 af[2], bfr[2];

  for (int T = 0; T < NT; ++T) {
    const unsigned char* base = lds + (T & 1) * 65536;
#pragma unroll
    for (int ph = 0; ph < 4; ++ph) {
      const int ks = ph >> 1, mq = ph & 1;
      const unsigned char* aU = base + ks * 32768;
      const unsigned char* bU = aU + 16384;
      if (mq == 0) {
#pragma unroll
        for (int ni = 0; ni < 2; ++ni)
          bfr[ni] = read_frag(bU, wc * 64 + ni * 32 + l31);
#pragma unroll
        for (int mi = 0; mi < 2; ++mi)
          af[mi] = read_frag(aU, wr * 128 + mi * 32 + l31);
      } else {
#pragma unroll
        for (int mi = 0; mi < 2; ++mi)
          af[mi] = read_frag(aU, wr * 128 + (2 + mi) * 32 + l31);
      }
      __builtin_amdgcn_sched_barrier(0);            // reads issue first
      const int sug = 4 * T + ((ph == 0) ? 6 : (ph == 1) ? 9 : (ph == 2) ? 8 : 11);
      if (sug < NUNITS) stage(sug);
      asm volatile("s_waitcnt lgkmcnt(0)" ::: "memory");
      __builtin_amdgcn_sched_barrier(0);
      __builtin_amdgcn_s_setprio(1);
#pragma unroll
      for (int mi = 0; mi < 2; ++mi)
#pragma unroll
        for (int ni = 0; ni < 2; ++ni)
          acc[mq * 2 + mi][ni] = __builtin_amdgcn_mfma_scale_f32_32x32x64_f8f6f4(
              af[mi], bfr[ni], acc[mq * 2 + mi][ni],
              0, 0,            // cbsz=fp8, blgp=fp8
              0, SCALE1,       // A: opsel 0, scale 1.0
              0, SCALE1);      // B: opsel 0, scale 1.0
      __builtin_amdgcn_s_setprio(0);
      if (ph == 3 && T < NT - 1) {
        if (T < NT - 2) asm volatile("s_waitcnt vmcnt(6)" ::: "memory");
        else            asm volatile("s_waitcnt vmcnt(0)" ::: "memory");
      }
      __builtin_amdgcn_s_barrier();
    }
  }

  // ---- epilogue: per-row sum of exp(logit) over 256 vocab cols ------------
  // 32x32 C/D: col = lane&31, row = (reg&3) + 8*(reg>>2) + 4*(lane>>5).
  // Undo the C*8 pre-scale: logit = acc * 0.125.
#pragma unroll
  for (int mi = 0; mi < 4; ++mi) {
    float p[16];
#pragma unroll
    for (int r = 0; r < 16; ++r)
      p[r] = __expf(acc[mi][0][r] * 0.125f) + __expf(acc[mi][1][r] * 0.125f);
#pragma unroll
    for (int m = 1; m < 32; m <<= 1)
#pragma unroll
      for (int r = 0; r < 16; ++r) p[r] += __shfl_xor(p[r], m, 64);
    if (l31 == 0) {
#pragma unroll
      for (int r = 0; r < 16; ++r) {
        const int row = brow + wr * 128 + mi * 32 + (r & 3) + 8 * (r >> 2) + 4 * lh;
        atomicAdd(&sumexp[row], p[r]);
      }
    }
  }
}

// ---------------- fallback path (fp32 reg-staged, 128^2 tile) --------------
#define FBM 128
#define FBN 128
#define FBK 64
#define FNK (DIM / FBK)
#define FTHREADS 512

__global__ __launch_bounds__(FTHREADS, 4)
void lce_gemm_f32(const float* __restrict__ E, const float* __restrict__ C,
                  float* __restrict__ sumexp) {
  extern __shared__ unsigned char lds[];
  const int tid  = threadIdx.x;
  const int brow = blockIdx.x * FBM;
  const int bcol = blockIdx.y * FBN;

  float4 ra[4], rb[4];
  auto ld = [&](int k0) {
#pragma unroll
    for (int i = 0; i < 4; ++i) {
      int f = tid + i * FTHREADS;
      int r = f >> 4;
      int c = (f & 15) << 2;
      ra[i] = *reinterpret_cast<const float4*>(&E[(size_t)(brow + r) * DIM + k0 + c]);
      rb[i] = *reinterpret_cast<const float4*>(&C[(size_t)(bcol + r) * DIM + k0 + c]);
    }
  };
  auto st = [&](int buf) {
    unsigned char* a = lds + buf * 32768;
    unsigned char* b = a + 16384;
#pragma unroll
    for (int i = 0; i < 4; ++i) {
      int f  = tid + i * FTHREADS;
      int r  = f >> 4;
      int cbb = (f & 15) << 3;
      int off = r * 128 + (cbb ^ ((r & 7) << 4));
      union { bf16_t h[4]; unsigned long long u; } pa, pb;
      pa.h[0] = (bf16_t)ra[i].x; pa.h[1] = (bf16_t)ra[i].y;
      pa.h[2] = (bf16_t)ra[i].z; pa.h[3] = (bf16_t)ra[i].w;
      pb.h[0] = (bf16_t)rb[i].x; pb.h[1] = (bf16_t)rb[i].y;
      pb.h[2] = (bf16_t)rb[i].z; pb.h[3] = (bf16_t)rb[i].w;
      *reinterpret_cast<unsigned long long*>(a + off) = pa.u;
      *reinterpret_cast<unsigned long long*>(b + off) = pb.u;
    }
  };

  f32x4 acc[4][2];
#pragma unroll
  for (int mi = 0; mi < 4; ++mi)
#pragma unroll
    for (int ni = 0; ni < 2; ++ni) acc[mi][ni] = (f32x4){0.f, 0.f, 0.f, 0.f};

  const int lane = tid & 63, wid = tid >> 6;
  const int wr = wid >> 2, wc = wid & 3;
  const int l15 = lane & 15, lg = lane >> 4;
  const int swz = (l15 & 7) << 4;

  auto comp = [&](int buf) {
    const unsigned char* a = lds + buf * 32768;
    const unsigned char* b = a + 16384;
#pragma unroll
    for (int kk = 0; kk < 2; ++kk) {
      const int cbase = (kk * 64 + lg * 16) ^ swz;
      bf16x8 af[4], bfr[2];
#pragma unroll
      for (int mi = 0; mi < 4; ++mi)
        af[mi] = *reinterpret_cast<const bf16x8*>(
            a + (wr * 64 + mi * 16 + l15) * 128 + cbase);
#pragma unroll
      for (int ni = 0; ni < 2; ++ni)
        bfr[ni] = *reinterpret_cast<const bf16x8*>(
            b + (wc * 32 + ni * 16 + l15) * 128 + cbase);
#pragma unroll
      for (int mi = 0; mi < 4; ++mi)
#pragma unroll
        for (int ni = 0; ni < 2; ++ni)
          acc[mi][ni] = __builtin_amdgcn_mfma_f32_16x16x32_bf16(
              af[mi], bfr[ni], acc[mi][ni], 0, 0, 0);
    }
  };

  ld(0);
  st(0);
  for (int kt = 0; kt < FNK; ++kt) {
    __syncthreads();
    if (kt + 1 < FNK) ld((kt + 1) * FBK);
    comp(kt & 1);
    if (kt + 1 < FNK) st((kt + 1) & 1);
  }

#pragma unroll
  for (int mi = 0; mi < 4; ++mi) {
    float p[4];
#pragma unroll
    for (int j = 0; j < 4; ++j)
      p[j] = __expf(acc[mi][0][j]) + __expf(acc[mi][1][j]);
#pragma unroll
    for (int m = 1; m < 16; m <<= 1)
#pragma unroll
      for (int j = 0; j < 4; ++j) p[j] += __shfl_xor(p[j], m, 64);
    if (l15 == 0) {
      int row = brow + wr * 64 + mi * 16 + lg * 4;
#pragma unroll
      for (int j = 0; j < 4; ++j) atomicAdd(&sumexp[row + j], p[j]);
    }
  }
}

// ---------------- exact fp32 target logit, one wave per row ----------------
__global__ __launch_bounds__(256)
void lce_tgt(const float* __restrict__ E, const float* __restrict__ C,
             const int* __restrict__ T, float* __restrict__ tgt) {
  int w = (int)((blockIdx.x * blockDim.x + threadIdx.x) >> 6);
  int lane = threadIdx.x & 63;
  if (w >= N_ROWS) return;
  int t = T[w];
  float s = 0.f;
  if (t != IGN) {
    const float4* er = reinterpret_cast<const float4*>(E + (size_t)w * DIM);
    const float4* cr = reinterpret_cast<const float4*>(C + (size_t)t * DIM);
#pragma unroll
    for (int i = 0; i < DIM / 4 / 64; ++i) {
      float4 a = er[lane + i * 64];
      float4 b = cr[lane + i * 64];
      s = fmaf(a.x, b.x, s); s = fmaf(a.y, b.y, s);
      s = fmaf(a.z, b.z, s); s = fmaf(a.w, b.w, s);
    }
#pragma unroll
    for (int m = 1; m < 64; m <<= 1) s += __shfl_xor(s, m, 64);
  }
  if (lane == 0) tgt[w] = s;
}

// ---------------- final scalar reduce --------------------------------------
__global__ __launch_bounds__(256)
void lce_finalize(const float* __restrict__ sumexp, const float* __restrict__ tgt,
                  const int* __restrict__ T, float* __restrict__ out) {
  int tid = threadIdx.x;
  float nll = 0.f, cnt = 0.f;
  for (int n = tid; n < N_ROWS; n += 256) {
    if (T[n] != IGN) {
      nll += logf(sumexp[n]) - tgt[n];
      cnt += 1.f;
    }
  }
#pragma unroll
  for (int m = 1; m < 64; m <<= 1) {
    nll += __shfl_xor(nll, m, 64);
    cnt += __shfl_xor(cnt, m, 64);
  }
  __shared__ float sn[4], sc[4];
  if ((tid & 63) == 0) { sn[tid >> 6] = nll; sc[tid >> 6] = cnt; }
  __syncthreads();
  if (tid == 0) {
    float a = 0.f, b = 0.f;
#pragma unroll
    for (int i = 0; i < 4; ++i) { a += sn[i]; b += sc[i]; }
    out[0] = a / fmaxf(b, 1.f);
  }
}

extern "C" void kernel_launch(void* const* d_in, const int* in_sizes, int n_in,
                              void* d_out, int out_size, void* d_ws, size_t ws_size,
                              hipStream_t stream) {
  const float* E = (const float*)d_in[0];
  const float* C = (const float*)d_in[1];
  const int*   T = (const int*)d_in[2];
  float* out = (float*)d_out;

  unsigned char* ws = (unsigned char*)d_ws;
  float* sumexp = (float*)ws;                        // 16 KB
  float* tgt    = (float*)(ws + 16384);              // 16 KB
  unsigned char* E8 = ws + 32768;                    // 8 MB
  unsigned char* C8 = E8 + (size_t)N_ROWS * DIM;     // 128 MB

  const size_t need = 32768 + (size_t)N_ROWS * DIM + (size_t)VOCAB * DIM;

  hipMemsetAsync(sumexp, 0, N_ROWS * sizeof(float), stream);

  if (ws_size >= need) {
    cvt_fp8<<<2048, 256, 0, stream>>>(E, E8, (long)N_ROWS * DIM / 16, 1.0f);
    cvt_fp8<<<2048, 256, 0, stream>>>(C, C8, (long)VOCAB * DIM / 16, 8.0f);
    lce_gemm_fp8<<<dim3((N_ROWS / BM) * (VOCAB / BN)), 512, 131072, stream>>>(E8, C8, sumexp);
  } else {
    lce_gemm_f32<<<dim3(N_ROWS / FBM, VOCAB / FBN), FTHREADS, 65536, stream>>>(E, C, sumexp);
  }

  lce_tgt<<<dim3((N_ROWS * 64) / 256), 256, 0, stream>>>(E, C, T, tgt);
  lce_finalize<<<dim3(1), 256, 0, stream>>>(sumexp, tgt, T, out);
}